// Round 7
// baseline (454.229 us; speedup 1.0000x reference)
//
#include <hip/hip_runtime.h>
#include <hip/hip_bf16.h>

// LSTM: S=128, N=2048, H=128, O=128. fp32 buffers, bf16 MFMA internally.
// R7: 256 persistent blocks x 256 threads (4 waves); block b owns samples
// [8b, 8b+8). Sum-of-pipes model (R6 calibration): step time ~ sum of
// per-CU pipe demands x convoy factor. This layout keeps MFMA/trans demand
// per CU identical but HALVES the LDS A-frag read amplification (4 waves x
// 8 ds_read_b128 vs 8 x 8) and halves the barrier convoy width, while
// using all 256 CUs. M=16 MFMA tiles are half-padded: LDS x rows 8-15
// duplicate rows 0-7 (same cache lines, no OOB); junk rows are inert
// (MFMA rows independent; h bounded by o*tanh; no NaN/inf reachable).
//   - R6 keeps: xgA/xgB accumulator role swap (h-MFMA accumulates into xg
//     seeds), log2e folded into weights, incremental pointers.
//   - R5 lesson: A-frags must come from LDS (global per-lane loads are
//     transpose-shaped -> L1 convoy). R1 lesson: lgkmcnt-only barrier.

#define S_LEN   128
#define N_BATCH 2048
#define H_DIM   128
#define O_DIM   128

using short8  = __attribute__((ext_vector_type(8))) short;  // 8 bf16 (4 VGPRs)
using short4v = __attribute__((ext_vector_type(4))) short;  // 4 bf16
using floatx4 = __attribute__((ext_vector_type(4))) float;  // 4 fp32 acc
typedef unsigned short u16;

#define ROWP     264                 // LDS row pitch in bf16 elems (256 + 8 pad)
#define BUFELEMS (16 * ROWP)         // one tile buffer: 16 rows x [x(0:128)|h(128:256)]

__device__ __forceinline__ u16 f2b(float f) {   // RNE f32->bf16
    unsigned int u = __float_as_uint(f);
    return (u16)((u + 0x7FFF + ((u >> 16) & 1)) >> 16);
}
__device__ __forceinline__ short8 pack8s(const float* p, float k) {  // scaled pack
    short8 r;
#pragma unroll
    for (int i = 0; i < 8; ++i) r[i] = (short)f2b(k * p[i]);
    return r;
}
__device__ __forceinline__ short4v pack4(float4 f) {
    short4v r;
    r[0] = (short)f2b(f.x); r[1] = (short)f2b(f.y);
    r[2] = (short)f2b(f.z); r[3] = (short)f2b(f.w);
    return r;
}
__device__ __forceinline__ float tanhf_fast(float v) {   // tanh(c), unscaled input
    return 1.0f - 2.0f * __builtin_amdgcn_rcpf(1.0f + __builtin_amdgcn_exp2f(2.8853900817779268f * v));
}

// lgkmcnt-only barrier: LDS ordered, global loads/stores stay in flight.
__device__ __forceinline__ void lds_barrier() {
    asm volatile("s_waitcnt lgkmcnt(0)" ::: "memory");
    __builtin_amdgcn_s_barrier();
}

// One recurrence step. g[t][cf] enter holding xg_s (scaled, bias-seeded);
// n[t][cf] receive xg_{s+1}. All control flags are wave-uniform.
__device__ __forceinline__ void step_body(
    int s,
    floatx4 (&g)[4][2], floatx4 (&n)[4][2],
    const short* shb, short* shn, short* stagep,
    const short8 (&wh)[4][4][2], const short8 (&wx)[4][4][2],
    const short8 (&wo)[4][2],
    const float (&biasv)[4][2], const float (&bo)[2],
    float (&cc)[2][4], float4& xc0, float4& xc1,
    const float*& xptr, float*& pcur,
    int arow, int hcolb, int qrow, bool predrow)
{
    floatx4 ao[2];
#pragma unroll
    for (int cf = 0; cf < 2; ++cf)
        ao[cf] = floatx4{bo[cf], bo[cf], bo[cf], bo[cf]};

    // ---- critical path: h_{s-1} MFMA (K=128), accumulate into xg seeds ----
#pragma unroll
    for (int kk = 0; kk < 4; ++kk) {
        short8 ah = *reinterpret_cast<const short8*>(&shb[arow + 128 + kk * 32]);
#pragma unroll
        for (int t = 0; t < 4; ++t) {
            g[t][0] = __builtin_amdgcn_mfma_f32_16x16x32_bf16(ah, wh[t][kk][0], g[t][0], 0, 0, 0);
            g[t][1] = __builtin_amdgcn_mfma_f32_16x16x32_bf16(ah, wh[t][kk][1], g[t][1], 0, 0, 0);
        }
        ao[0] = __builtin_amdgcn_mfma_f32_16x16x32_bf16(ah, wo[kk][0], ao[0], 0, 0, 0);
        ao[1] = __builtin_amdgcn_mfma_f32_16x16x32_bf16(ah, wo[kk][1], ao[1], 0, 0, 0);
    }

    // pred_{s-1}: rows quad*4+r valid only for quad<2 (8 samples/block)
    if (s > 0 && predrow) {
#pragma unroll
        for (int cf = 0; cf < 2; ++cf)
#pragma unroll
            for (int r = 0; r < 4; ++r)
                pcur[(size_t)r * O_DIM + cf * 16] = ao[cf][r];
    }
    if (s > 0) pcur += (size_t)N_BATCH * O_DIM;

    // ---- off-path: xg_{s+1} from x-region of B_s ----
    if (s < S_LEN - 1) {
#pragma unroll
        for (int t = 0; t < 4; ++t) {
            n[t][0] = floatx4{biasv[t][0], biasv[t][0], biasv[t][0], biasv[t][0]};
            n[t][1] = floatx4{biasv[t][1], biasv[t][1], biasv[t][1], biasv[t][1]};
        }
#pragma unroll
        for (int kk = 0; kk < 4; ++kk) {
            short8 axv = *reinterpret_cast<const short8*>(&shb[arow + kk * 32]);
#pragma unroll
            for (int t = 0; t < 4; ++t) {
                n[t][0] = __builtin_amdgcn_mfma_f32_16x16x32_bf16(axv, wx[t][kk][0], n[t][0], 0, 0, 0);
                n[t][1] = __builtin_amdgcn_mfma_f32_16x16x32_bf16(axv, wx[t][kk][1], n[t][1], 0, 0, 0);
            }
        }
    }

    // stage x_{s+2} into B_{s+1}; refill xcur with x_{s+3}
    if (s <= S_LEN - 3) {
        *reinterpret_cast<short4v*>(stagep)     = pack4(xc0);
        *reinterpret_cast<short4v*>(stagep + 4) = pack4(xc1);
    }
    if (s <= S_LEN - 4) {
        xc0 = *reinterpret_cast<const float4*>(xptr);
        xc1 = *reinterpret_cast<const float4*>(xptr + 4);
    }
    xptr += (size_t)N_BATCH * H_DIM;

    // ---- activations + state update; h -> LDS (rows quad*4+r, 2 cols) ----
#pragma unroll
    for (int cf = 0; cf < 2; ++cf) {
#pragma unroll
        for (int r = 0; r < 4; ++r) {
            float iv = __builtin_amdgcn_rcpf(1.0f + __builtin_amdgcn_exp2f(g[0][cf][r]));
            float fv = __builtin_amdgcn_rcpf(1.0f + __builtin_amdgcn_exp2f(g[1][cf][r]));
            float gv = 1.0f - 2.0f * __builtin_amdgcn_rcpf(1.0f + __builtin_amdgcn_exp2f(g[2][cf][r]));
            float ov = __builtin_amdgcn_rcpf(1.0f + __builtin_amdgcn_exp2f(g[3][cf][r]));
            cc[cf][r] = fv * cc[cf][r] + iv * gv;
            shn[(qrow + r) * ROWP + hcolb + cf * 16] = (short)f2b(ov * tanhf_fast(cc[cf][r]));
        }
    }

    lds_barrier();
}

__global__ __launch_bounds__(256, 1)
void lstm_persist(const float* __restrict__ x,
                  const float* __restrict__ W_ih,
                  const float* __restrict__ W_hh,
                  const float* __restrict__ b_ih,
                  const float* __restrict__ b_hh,
                  const float* __restrict__ W_out,
                  const float* __restrict__ b_out,
                  float* __restrict__ pred) {
    __shared__ short sh[2 * BUFELEMS];

    const int tid  = (int)threadIdx.x;
    const int wave = tid >> 6;           // 0..3
    const int lane = tid & 63;
    const int quad = lane >> 4;          // 0..3
    const int l15  = lane & 15;
    const int n0   = (int)blockIdx.x * 8;   // 8 samples per block

    const float kSig = -1.4426950408889634f;
    const float kG   =  2.8853900817779268f;

    // ---- weights: wave w owns gate cols [w*32, w*32+32) => 2 frags (cf) ----
    short8 wx[4][4][2], wh[4][4][2], wo[4][2];
    float  biasv[4][2], bo[2];
#pragma unroll
    for (int t = 0; t < 4; ++t) {
        const float sc = (t == 2) ? kG : kSig;
#pragma unroll
        for (int cf = 0; cf < 2; ++cf) {
            const int g = t * 128 + wave * 32 + cf * 16 + l15;
#pragma unroll
            for (int kk = 0; kk < 4; ++kk) {
                wx[t][kk][cf] = pack8s(W_ih + g * H_DIM + kk * 32 + quad * 8, sc);
                wh[t][kk][cf] = pack8s(W_hh + g * H_DIM + kk * 32 + quad * 8, sc);
            }
            biasv[t][cf] = sc * (b_ih[g] + b_hh[g]);
        }
    }
#pragma unroll
    for (int cf = 0; cf < 2; ++cf) {
        const int ocol = wave * 32 + cf * 16 + l15;
#pragma unroll
        for (int kk = 0; kk < 4; ++kk)
            wo[kk][cf] = pack8s(W_out + ocol * H_DIM + kk * 32 + quad * 8, 1.0f);
        bo[cf] = b_out[ocol];
    }

    // x loader: 256 threads stage 16 rows x 128 cols; rows 8-15 duplicate
    // rows 0-7 (row&7): junk-safe, no OOB, same cache lines.
    const int xm  = tid >> 4;            // LDS row 0..15
    const int xq  = (tid & 15) * 8;      // col 0..120 step 8
    const int xgr = n0 + (xm & 7);       // global sample row (duplicated)

    // ---- prologue ----
    for (int i = tid; i < 16 * 128; i += 256)
        sh[(i >> 7) * ROWP + 128 + (i & 127)] = 0;   // h_{-1} = 0
    {   // x_0 -> buf1 x-region, x_1 -> buf0 x-region
        const float* r0 = x + (size_t)xgr * H_DIM + xq;
        const float* r1 = x + ((size_t)N_BATCH + xgr) * H_DIM + xq;
        *reinterpret_cast<short4v*>(&sh[BUFELEMS + xm * ROWP + xq])     = pack4(*reinterpret_cast<const float4*>(r0));
        *reinterpret_cast<short4v*>(&sh[BUFELEMS + xm * ROWP + xq + 4]) = pack4(*reinterpret_cast<const float4*>(r0 + 4));
        *reinterpret_cast<short4v*>(&sh[xm * ROWP + xq])     = pack4(*reinterpret_cast<const float4*>(r1));
        *reinterpret_cast<short4v*>(&sh[xm * ROWP + xq + 4]) = pack4(*reinterpret_cast<const float4*>(r1 + 4));
    }
    float4 xc0 = *reinterpret_cast<const float4*>(x + ((size_t)2 * N_BATCH + xgr) * H_DIM + xq);
    float4 xc1 = *reinterpret_cast<const float4*>(x + ((size_t)2 * N_BATCH + xgr) * H_DIM + xq + 4);
    __syncthreads();

    const int arow  = l15 * ROWP + quad * 8;   // A-frag: A[m=l15][k=quad*8+..]
    const int hcolb = 128 + wave * 32 + l15;   // h col base (cf adds 16)
    const int qrow  = quad * 4;
    const bool predrow = (quad < 2);           // rows 0-7 valid

    // xg_0 from buf1 x-region -> xgA
    floatx4 xgA[4][2], xgB[4][2];
#pragma unroll
    for (int t = 0; t < 4; ++t) {
        xgA[t][0] = floatx4{biasv[t][0], biasv[t][0], biasv[t][0], biasv[t][0]};
        xgA[t][1] = floatx4{biasv[t][1], biasv[t][1], biasv[t][1], biasv[t][1]};
    }
#pragma unroll
    for (int kk = 0; kk < 4; ++kk) {
        short8 a = *reinterpret_cast<const short8*>(&sh[BUFELEMS + arow + kk * 32]);
#pragma unroll
        for (int t = 0; t < 4; ++t) {
            xgA[t][0] = __builtin_amdgcn_mfma_f32_16x16x32_bf16(a, wx[t][kk][0], xgA[t][0], 0, 0, 0);
            xgA[t][1] = __builtin_amdgcn_mfma_f32_16x16x32_bf16(a, wx[t][kk][1], xgA[t][1], 0, 0, 0);
        }
    }
    __syncthreads();   // buf1-x reads done before step 0 stages x_2 there

    float cc[2][4] = {{0.f,0.f,0.f,0.f},{0.f,0.f,0.f,0.f}};

    short* const sA = sh;
    short* const sB = sh + BUFELEMS;
    short* const stageA = &sA[xm * ROWP + xq];
    short* const stageB = &sB[xm * ROWP + xq];

    const float* xptr = x + ((size_t)3 * N_BATCH + xgr) * H_DIM + xq;
    float*       pcur = pred + ((size_t)(n0 + qrow)) * O_DIM + wave * 32 + l15;

    // ---- main recurrence, 2-step unrolled with xgA/xgB role swap ----
    for (int it = 0; it < S_LEN / 2; ++it) {
        step_body(2 * it,     xgA, xgB, sA, sB, stageB, wh, wx, wo, biasv, bo,
                  cc, xc0, xc1, xptr, pcur, arow, hcolb, qrow, predrow);
        step_body(2 * it + 1, xgB, xgA, sB, sA, stageA, wh, wx, wo, biasv, bo,
                  cc, xc0, xc1, xptr, pcur, arow, hcolb, qrow, predrow);
    }

    // ---- epilogue: pred_{S-1} from h_127 in buf0 ----
    floatx4 ao[2];
#pragma unroll
    for (int cf = 0; cf < 2; ++cf)
        ao[cf] = floatx4{bo[cf], bo[cf], bo[cf], bo[cf]};
#pragma unroll
    for (int kk = 0; kk < 4; ++kk) {
        short8 ah = *reinterpret_cast<const short8*>(&sh[arow + 128 + kk * 32]);
        ao[0] = __builtin_amdgcn_mfma_f32_16x16x32_bf16(ah, wo[kk][0], ao[0], 0, 0, 0);
        ao[1] = __builtin_amdgcn_mfma_f32_16x16x32_bf16(ah, wo[kk][1], ao[1], 0, 0, 0);
    }
    if (predrow) {
#pragma unroll
        for (int cf = 0; cf < 2; ++cf)
#pragma unroll
            for (int r = 0; r < 4; ++r)
                pcur[(size_t)r * O_DIM + cf * 16] = ao[cf][r];
    }
}

extern "C" void kernel_launch(void* const* d_in, const int* in_sizes, int n_in,
                              void* d_out, int out_size, void* d_ws, size_t ws_size,
                              hipStream_t stream) {
    const float* x    = (const float*)d_in[0];
    const float* Wih  = (const float*)d_in[1];
    const float* Whh  = (const float*)d_in[2];
    const float* bih  = (const float*)d_in[3];
    const float* bhh  = (const float*)d_in[4];
    const float* Wout = (const float*)d_in[5];
    const float* bout = (const float*)d_in[6];
    float* pred = (float*)d_out;

    lstm_persist<<<dim3(N_BATCH / 8), dim3(256), 0, stream>>>(
        x, Wih, Whh, bih, bhh, Wout, bout, pred);
}